// Round 8
// baseline (145.067 us; speedup 1.0000x reference)
//
#include <hip/hip_runtime.h>
#include <math.h>

#define NLVL 8
#define PR1 2654435761u
#define PR2 805459861u

typedef __fp16    h2v   __attribute__((ext_vector_type(2)));   // cvt_pkrtz return type
typedef _Float16  half4 __attribute__((ext_vector_type(4)));   // 16x16x16 MFMA A/B operand
typedef float     floatx4 __attribute__((ext_vector_type(4)));

// Legacy K=16 MFMA builtins use the no-underscore dtype suffix on gfx950.
#define MFMA16(a,b,c) __builtin_amdgcn_mfma_f32_16x16x16f16(a,b,c,0,0,0)

union UH2 { unsigned u; h2v h; };

struct Res8 { float r[NLVL]; };

__device__ __forceinline__ unsigned pk2(float a, float b) {
    UH2 c; c.h = __builtin_amdgcn_cvt_pkrtz(a, b); return c.u;
}
__device__ __forceinline__ unsigned pkrelu(float a, float b) {
    UH2 c; c.h = __builtin_amdgcn_cvt_pkrtz(a, b);
    h2v z = {(__fp16)0.f, (__fp16)0.f};
    c.h = __builtin_elementwise_max(c.h, z);
    return c.u;
}
__device__ __forceinline__ half4 as_h4(uint2 u) {
    union { uint2 u; half4 h; } c; c.u = u; return c.h;
}
__device__ __forceinline__ h2v lerp2(h2v a, h2v b, h2v t) {
    return a + t * (b - a);
}

// Fused NGP, register-resident MLP chain (C/D frag of 16x16x16f16 == B frag of
// the next K=16 chunk -> inter-layer transpose is 2x cvt_pkrtz, zero LDS).
// Round-8 pressure fixes: t-loop unrolled 2 (not 4) and L2/L4 accumulation
// split into 2 parallel MFMA chains + v_add, so peak VGPR fits the 128 cap of
// launch_bounds(512,4) without spills or tile serialization.
__global__ __launch_bounds__(512, 4)
void ngp_mfma_kernel(const float* __restrict__ x,
                     const float* __restrict__ table,
                     const float* __restrict__ w1,
                     const float* __restrict__ w2,
                     const float* __restrict__ r1,
                     const float* __restrict__ r2,
                     const float* __restrict__ r3,
                     float* __restrict__ out,
                     int N, int iters, Res8 res)
{
    __shared__ unsigned tab[NLVL * 1024];   // 32 KB packed f16x2
    __shared__ unsigned hstg[8][640];       // 20 KB: 64 pts x 10 dw (stride-10 pad)

    const int tid  = threadIdx.x;
    const int lane = tid & 63, wv = tid >> 6;
    const int m16  = lane & 15, q = lane >> 4;

    {   // stage table: 8192 float2 -> 8192 packed dwords (16/thread @ 512 thr)
        const float2* src = (const float2*)table;
        #pragma unroll
        for (int k = 0; k < 16; ++k) {
            int i = tid + 512 * k;
            float2 v = src[i];
            tab[i] = pk2(v.x, v.y);
        }
    }

    // Preload weight A-frags (W^T) for 16x16x16: A[m=m16][k=q*4+j]. 56 VGPRs.
    half4 A1[4], A2[4], A3[4], A4[4][4];
    #pragma unroll
    for (int mo = 0; mo < 4; ++mo)
        #pragma unroll
        for (int j = 0; j < 4; ++j) {
            int k = q * 4 + j;
            A1[mo][j] = (_Float16)w1[k * 64 + mo * 16 + m16];
            A3[mo][j] = (_Float16)r1[k * 64 + mo * 16 + m16];
            A2[mo][j] = (_Float16)w2[(mo * 16 + k) * 16 + m16];   // mo = K-chunk here
            #pragma unroll
            for (int kc = 0; kc < 4; ++kc)
                A4[kc][mo][j] = (_Float16)r2[(kc * 16 + k) * 64 + mo * 16 + m16];
        }
    float r3v[16];
    #pragma unroll
    for (int mo = 0; mo < 4; ++mo)
        #pragma unroll
        for (int r = 0; r < 4; ++r)
            r3v[mo * 4 + r] = r3[mo * 16 + q * 4 + r];

    __syncthreads();                        // table visible; only barrier in kernel

    unsigned* hs = hstg[wv];
    const char* tabb = (const char*)tab;
    const floatx4 cz = {0.f, 0.f, 0.f, 0.f};

    #pragma unroll 1
    for (int it = 0; it < iters; ++it) {
        const int pbase = (it * (int)gridDim.x + (int)blockIdx.x) * 512;
        int p = pbase + tid;                 // grid*threads*iters == N exactly

        float px = x[3 * p + 0] + 0.5f;
        float py = x[3 * p + 1] + 0.5f;
        float pz = x[3 * p + 2] + 0.5f;

        // ---- encode: 8 levels, 7-lerp trilinear tree on packed f16 ----
        unsigned hd[8];
        #pragma unroll
        for (int l = 0; l < NLVL; ++l) {
            const float rf = res.r[l];
            float fx = px * rf, fy = py * rf, fz = pz * rf;
            float bx = floorf(fx), by = floorf(fy), bz = floorf(fz);
            UH2 wxp, wyp, wzp;
            wxp.h = __builtin_amdgcn_cvt_pkrtz(fx - bx, fx - bx);
            wyp.h = __builtin_amdgcn_cvt_pkrtz(fy - by, fy - by);
            wzp.h = __builtin_amdgcn_cvt_pkrtz(fz - bz, fz - bz);
            unsigned ix = (unsigned)bx, iy = (unsigned)by, iz = (unsigned)bz;
            unsigned x0 = (ix << 2) & 4092u,          x1 = (x0 + 4u) & 4092u;
            unsigned y0 = ((iy * PR1) << 2) & 4092u,  y1 = (y0 + (PR1 << 2)) & 4092u;
            unsigned z0 = ((iz * PR2) << 2) & 4092u,  z1 = (z0 + (PR2 << 2)) & 4092u;
            unsigned a00 = x0 ^ y0, a01 = x0 ^ y1, a10 = x1 ^ y0, a11 = x1 ^ y1;
            const char* tlb = tabb + (l << 12);
            UH2 c000, c001, c010, c011, c100, c101, c110, c111;
            c000.u = *(const unsigned*)(tlb + (a00 ^ z0));
            c001.u = *(const unsigned*)(tlb + (a00 ^ z1));
            c010.u = *(const unsigned*)(tlb + (a01 ^ z0));
            c011.u = *(const unsigned*)(tlb + (a01 ^ z1));
            c100.u = *(const unsigned*)(tlb + (a10 ^ z0));
            c101.u = *(const unsigned*)(tlb + (a10 ^ z1));
            c110.u = *(const unsigned*)(tlb + (a11 ^ z0));
            c111.u = *(const unsigned*)(tlb + (a11 ^ z1));
            h2v zz00 = lerp2(c000.h, c001.h, wzp.h);
            h2v zz01 = lerp2(c010.h, c011.h, wzp.h);
            h2v zz10 = lerp2(c100.h, c101.h, wzp.h);
            h2v zz11 = lerp2(c110.h, c111.h, wzp.h);
            h2v yy0  = lerp2(zz00, zz01, wyp.h);
            h2v yy1  = lerp2(zz10, zz11, wyp.h);
            UH2 r; r.h = lerp2(yy0, yy1, wxp.h);
            hd[l] = r.u;                     // packed features (2l, 2l+1)
        }
        {   // encode->MLP transpose staging, stride 10 (4 b64 writes, <=4-way)
            unsigned* hp = hs + lane * 10;
            *(uint2*)&hp[0] = make_uint2(hd[0], hd[1]);
            *(uint2*)&hp[2] = make_uint2(hd[2], hd[3]);
            *(uint2*)&hp[4] = make_uint2(hd[4], hd[5]);
            *(uint2*)&hp[6] = make_uint2(hd[6], hd[7]);
        }

        // ---- MLP: 4 tiles of 16 points, 2 tiles in flight (register budget) ----
        #pragma unroll 2
        for (int t = 0; t < 4; ++t) {
            half4 b1 = as_h4(*(const uint2*)&hs[(t * 16 + m16) * 10 + 2 * q]);

            // L1: 16->64, relu (4 independent MFMAs)
            half4 b2[4];
            #pragma unroll
            for (int mo = 0; mo < 4; ++mo) {
                floatx4 c = MFMA16(A1[mo], b1, cz);
                b2[mo] = as_h4(make_uint2(pkrelu(c[0], c[1]), pkrelu(c[2], c[3])));
            }
            // L2: 64->16 linear; 2 parallel accumulation chains + add
            floatx4 c2a = MFMA16(A2[0], b2[0], cz);
            floatx4 c2b = MFMA16(A2[1], b2[1], cz);
            c2a = MFMA16(A2[2], b2[2], c2a);
            c2b = MFMA16(A2[3], b2[3], c2b);
            floatx4 c2 = c2a + c2b;
            half4 b3 = as_h4(make_uint2(pk2(c2[0], c2[1]), pk2(c2[2], c2[3])));

            // L3: 16->64, relu
            half4 b4[4];
            #pragma unroll
            for (int mo = 0; mo < 4; ++mo) {
                floatx4 c = MFMA16(A3[mo], b3, cz);
                b4[mo] = as_h4(make_uint2(pkrelu(c[0], c[1]), pkrelu(c[2], c[3])));
            }
            // L4: 64->64 relu fused with L5 dot(r3); 2 parallel chains per mo
            float z = 0.f;
            #pragma unroll
            for (int mo = 0; mo < 4; ++mo) {
                floatx4 ca = MFMA16(A4[0][mo], b4[0], cz);
                floatx4 cb = MFMA16(A4[1][mo], b4[1], cz);
                ca = MFMA16(A4[2][mo], b4[2], ca);
                cb = MFMA16(A4[3][mo], b4[3], cb);
                floatx4 c = ca + cb;
                #pragma unroll
                for (int r = 0; r < 4; ++r)
                    z = fmaf(fmaxf(c[r], 0.f), r3v[mo * 4 + r], z);
            }
            z += __shfl_xor(z, 16);
            z += __shfl_xor(z, 32);
            if (lane < 16)
                out[pbase + wv * 64 + t * 16 + lane] = 1.0f / (1.0f + __expf(-z));
        }
    }
}

extern "C" void kernel_launch(void* const* d_in, const int* in_sizes, int n_in,
                              void* d_out, int out_size, void* d_ws, size_t ws_size,
                              hipStream_t stream)
{
    const float* x  = (const float*)d_in[0];
    const float* tb = (const float*)d_in[1];
    const float* w1 = (const float*)d_in[2];
    const float* w2 = (const float*)d_in[3];
    const float* r1 = (const float*)d_in[4];
    const float* r2 = (const float*)d_in[5];
    const float* r3 = (const float*)d_in[6];
    float* out = (float*)d_out;
    const int N = in_sizes[0] / 3;

    // Replicate numpy: B_SCALE = exp(log(20*0.5/2)/(L-1)); RES = floor(2*B^l)
    Res8 res;
    double b = exp(log(20.0 * 0.5 / 2.0) / (double)(NLVL - 1));
    for (int l = 0; l < NLVL; ++l)
        res.r[l] = (float)floor(2.0 * pow(b, (double)l));

    // 1024 blocks x 512 thr x 4 iters == 2M exactly. 52KB LDS -> 2 blocks/CU.
    const int blocks = 1024, threads = 512;
    const int iters = N / (blocks * threads);
    ngp_mfma_kernel<<<blocks, threads, 0, stream>>>(x, tb, w1, w2, r1, r2, r3,
                                                    out, N, iters, res);
}